// Round 5
// baseline (610.943 us; speedup 1.0000x reference)
//
#include <hip/hip_runtime.h>
#include <hip/hip_bf16.h>

// ---------- types & helpers ----------
typedef __attribute__((ext_vector_type(4))) float f32x4;
typedef __attribute__((ext_vector_type(8))) short s16x8;

__device__ __forceinline__ unsigned short f2bf(float f) {
    __hip_bfloat16 h = __float2bfloat16(f);
    return __builtin_bit_cast(unsigned short, h);
}
__device__ __forceinline__ float bf2f(unsigned short u) {
    return __builtin_bit_cast(float, ((unsigned)u) << 16);
}
__device__ __forceinline__ float2 bfpair(unsigned u) {
    float2 r;
    r.x = __builtin_bit_cast(float, u << 16);
    r.y = __builtin_bit_cast(float, u & 0xffff0000u);
    return r;
}
__device__ __forceinline__ void gload_lds16(const void* g, void* l) {
    __builtin_amdgcn_global_load_lds(
        (const __attribute__((address_space(1))) void*)g,
        (__attribute__((address_space(3))) void*)l, 16, 0, 0);
}

// ---------- convert x (fp32 -> bf16), 8 elems/thread, exact grid ----------
__global__ void k_f32_to_bf16(const float* __restrict__ in, unsigned short* __restrict__ out) {
    const long i = (long)blockIdx.x * 256 + threadIdx.x;   // 4,194,304 threads
    const float4 a = ((const float4*)in)[i * 2];
    const float4 b = ((const float4*)in)[i * 2 + 1];
    union { unsigned short h[8]; uint4 u; } r;
    r.h[0] = f2bf(a.x); r.h[1] = f2bf(a.y); r.h[2] = f2bf(a.z); r.h[3] = f2bf(a.w);
    r.h[4] = f2bf(b.x); r.h[5] = f2bf(b.y); r.h[6] = f2bf(b.z); r.h[7] = f2bf(b.w);
    ((uint4*)out)[i] = r.u;
}

// ---------- build W_cat^T [1536][512] bf16, coalesced via LDS 32x32 transpose ----------
__global__ __launch_bounds__(256)
void k_build_wcat(const float* __restrict__ Wq, const float* __restrict__ Wk,
                  const float* __restrict__ Wv, unsigned short* __restrict__ WcatT) {
    __shared__ float t[32][33];
    const int k0 = blockIdx.x * 32;          // 16 tiles over k
    const int j0 = blockIdx.y * 32;          // 48 tiles over j
    const float* src = (j0 < 512) ? Wq : (j0 < 1024 ? Wk : Wv);
    const int jc0 = j0 & 511;
    const int r = threadIdx.x >> 5, c = threadIdx.x & 31;
#pragma unroll
    for (int rr = 0; rr < 4; ++rr) {
        const int k = k0 + r + rr * 8;
        t[c][r + rr * 8] = src[(long)k * 512 + jc0 + c];   // coalesced read (j contiguous)
    }
    __syncthreads();
#pragma unroll
    for (int rr = 0; rr < 4; ++rr) {
        const int j = j0 + r + rr * 8;
        WcatT[(long)j * 512 + k0 + c] = f2bf(t[r + rr * 8][c]);  // coalesced write (k contiguous)
    }
}

// ---------- MFMA bf16 GEMM 128x128 (m97-style, proven 123us @ QKV shape) ----------
// Optional fused column sum-of-squares for cols < 1024 (Q,K norms), batch = row>>14.
#define BM 128
#define BN 128
#define BK 64

template<int OUT_BF16, int BIAS, int SSQF>
__global__ __launch_bounds__(256, 2)
void gemm_mfma(const unsigned short* __restrict__ A, const unsigned short* __restrict__ B,
               void* __restrict__ C_, const float* __restrict__ bias, float* __restrict__ ssq,
               int lda, int ldb, int ldc, int K, long sA, long sB, long sC) {
    __shared__ __align__(16) unsigned short As[BM * BK];
    __shared__ __align__(16) unsigned short Bs[BN * BK];
    __shared__ float ssq_lds[128];
    const int tid  = threadIdx.x;
    const int wave = tid >> 6;
    const int lane = tid & 63;
    const int wm = wave >> 1, wn = wave & 1;
    const int bm0 = blockIdx.y * BM;
    const int bn0 = blockIdx.x * BN;
    const long bz = blockIdx.z;
    A += bz * sA;
    B += bz * sB;

    const int l15 = lane & 15;
    const int l4  = lane >> 4;

    if (SSQF && tid < 128) ssq_lds[tid] = 0.f;

    f32x4 acc[4][4];
#pragma unroll
    for (int i = 0; i < 4; ++i)
#pragma unroll
        for (int j = 0; j < 4; ++j) acc[i][j] = (f32x4){0.f, 0.f, 0.f, 0.f};

    const int srow    = wave * 8 + (lane >> 3);
    const int schunk0 = lane & 7;
    const int arow_b  = wm * 64 + l15;
    const int brow_b  = wn * 64 + l15;

    const int nk = K / BK;
    for (int kt = 0; kt < nk; ++kt) {
        const int k0 = kt * BK;
#pragma unroll
        for (int i = 0; i < 4; ++i) {
            const int r  = i * 32 + srow;
            const int gc = schunk0 ^ (r & 7);
            gload_lds16(A + (long)(bm0 + r) * lda + (k0 + gc * 8), &As[(i * 32 + wave * 8) * BK]);
            gload_lds16(B + (long)(bn0 + r) * ldb + (k0 + gc * 8), &Bs[(i * 32 + wave * 8) * BK]);
        }
        __syncthreads();
        s16x8 af[4][2], bfr[4][2];
#pragma unroll
        for (int mi = 0; mi < 4; ++mi) {
            const int row = arow_b + mi * 16;
#pragma unroll
            for (int ki = 0; ki < 2; ++ki) {
                const int ch = (ki * 4 + l4) ^ (row & 7);
                af[mi][ki] = *(const s16x8*)&As[row * BK + ch * 8];
            }
        }
#pragma unroll
        for (int ni = 0; ni < 4; ++ni) {
            const int row = brow_b + ni * 16;
#pragma unroll
            for (int ki = 0; ki < 2; ++ki) {
                const int ch = (ki * 4 + l4) ^ (row & 7);
                bfr[ni][ki] = *(const s16x8*)&Bs[row * BK + ch * 8];
            }
        }
#pragma unroll
        for (int ki = 0; ki < 2; ++ki)
#pragma unroll
            for (int mi = 0; mi < 4; ++mi)
#pragma unroll
                for (int ni = 0; ni < 4; ++ni)
                    acc[mi][ni] = __builtin_amdgcn_mfma_f32_16x16x32_bf16(
                        af[mi][ki], bfr[ni][ki], acc[mi][ni], 0, 0, 0);
        __syncthreads();
    }

    // epilogue: C/D map col=lane&15, row=(lane>>4)*4+reg  [m89-verified]
#pragma unroll
    for (int mi = 0; mi < 4; ++mi) {
        const int row0 = bm0 + wm * 64 + mi * 16 + l4 * 4;
#pragma unroll
        for (int ni = 0; ni < 4; ++ni) {
            const int col = bn0 + wn * 64 + ni * 16 + l15;
            if (OUT_BF16) {
                unsigned short* C = (unsigned short*)C_ + bz * sC;
#pragma unroll
                for (int j = 0; j < 4; ++j)
                    C[(long)(row0 + j) * ldc + col] = f2bf(acc[mi][ni][j]);
            } else {
                float* C = (float*)C_ + bz * sC;
                const float bv = BIAS ? bias[col] : 0.f;
#pragma unroll
                for (int j = 0; j < 4; ++j)
                    C[(long)(row0 + j) * ldc + col] = acc[mi][ni][j] + bv;
            }
        }
    }
    // fused Q/K column sum-of-squares
    if (SSQF && bn0 < 1024) {
        const int b = bm0 >> 14;   // 16384 rows per batch
#pragma unroll
        for (int ni = 0; ni < 4; ++ni) {
            float s = 0.f;
#pragma unroll
            for (int mi = 0; mi < 4; ++mi)
#pragma unroll
                for (int j = 0; j < 4; ++j) s += acc[mi][ni][j] * acc[mi][ni][j];
            s += __shfl_xor(s, 16);
            s += __shfl_xor(s, 32);
            if (l4 == 0) atomicAdd(&ssq_lds[wn * 64 + ni * 16 + l15], s);
        }
        __syncthreads();
        if (tid < 128) atomicAdd(&ssq[b * 1024 + bn0 + tid], ssq_lds[tid]);
    }
}

// ---------- attn_raw[b,h,d,e] = sum_n K[n,d]*Q[n,e]  (per-chunk partial + atomics) ----------
__global__ __launch_bounds__(256)
void k_attn_partial(const unsigned short* __restrict__ QKV, float* __restrict__ attn) {
    __shared__ float Qt[64 * 64];
    __shared__ float Kt[64 * 64];
    const int t = threadIdx.x;
    const int chunk = blockIdx.x, h = blockIdx.y, b = blockIdx.z;
    const int td = t & 15, te = t >> 4;
    float acc[4][4] = {};
    const long base = ((long)b * 16384 + chunk * 256) * 1536 + h * 64;
    for (int tile = 0; tile < 4; ++tile) {
        __syncthreads();
#pragma unroll
        for (int i = 0; i < 16; ++i) {
            const int idx = i * 256 + t;
            const int row = idx >> 6, c = idx & 63;
            const long gq = base + (long)(tile * 64 + row) * 1536 + c;
            Qt[row * 64 + c] = bf2f(QKV[gq]);
            Kt[row * 64 + c] = bf2f(QKV[gq + 512]);
        }
        __syncthreads();
#pragma unroll 4
        for (int tok = 0; tok < 64; ++tok) {
            const f32x4 kv = *(const f32x4*)&Kt[tok * 64 + td * 4];
            const f32x4 qv = *(const f32x4*)&Qt[tok * 64 + te * 4];
#pragma unroll
            for (int i = 0; i < 4; ++i)
#pragma unroll
                for (int j = 0; j < 4; ++j) acc[i][j] += kv[i] * qv[j];
        }
    }
    float* arow = attn + ((long)(b * 8 + h)) * 4096;
#pragma unroll
    for (int i = 0; i < 4; ++i)
#pragma unroll
        for (int j = 0; j < 4; ++j)
            atomicAdd(&arow[(td * 4 + i) * 64 + te * 4 + j], acc[i][j]);
}

// ---------- normalize + softmax over e ----------
__global__ void k_softmax(float* __restrict__ attn, const float* __restrict__ sumsq,
                          const float* __restrict__ rescale) {
    const int bh = blockIdx.x;
    const int b = bh >> 3, h = bh & 7;
    const int d = threadIdx.x; // 64
    const float rs   = rescale[h];
    const float invk = rsqrtf(sumsq[b * 1024 + 512 + h * 64 + d]);
    __shared__ float invq[64];
    invq[d] = rsqrtf(sumsq[b * 1024 + h * 64 + d]);
    __syncthreads();
    float* row = attn + ((long)bh * 64 + d) * 64;
    float mx = -1e30f;
#pragma unroll
    for (int e = 0; e < 64; ++e) mx = fmaxf(mx, row[e] * invk * invq[e] * rs);
    float s = 0.f;
#pragma unroll
    for (int e = 0; e < 64; ++e) {
        const float l = expf(row[e] * invk * invq[e] * rs - mx);
        row[e] = l;
        s += l;
    }
    const float inv = 1.f / s;
#pragma unroll
    for (int e = 0; e < 64; ++e) row[e] *= inv;
}

// ---------- Weff^T[b][cout][h*64+e] = sum_d attn[b,h,d,e] * Wp[h*64+d][cout] ----------
__global__ __launch_bounds__(256)
void k_weff(const float* __restrict__ attn, const float* __restrict__ Wp,
            unsigned short* __restrict__ WeffT) {
    const int h = blockIdx.x, b = blockIdx.y;
    __shared__ float At[64 * 64];   // [d][e]
    __shared__ float Wt[64 * 128];  // [d][c]
    const int t = threadIdx.x;
    const float* arow = attn + ((long)(b * 8 + h)) * 4096;
    for (int i = 0; i < 16; ++i) At[i * 256 + t] = arow[i * 256 + t];
    const int e = t & 63, cs = t >> 6;
    for (int cc = 0; cc < 512; cc += 128) {
        __syncthreads();
        for (int i = 0; i < 32; ++i) {
            const int idx = i * 256 + t;
            const int d = idx >> 7, c = idx & 127;
            Wt[idx] = Wp[(long)(h * 64 + d) * 512 + cc + c];
        }
        __syncthreads();
        for (int i = 0; i < 32; ++i) {
            const int cl = cs * 32 + i;
            float acc = 0.f;
#pragma unroll
            for (int d = 0; d < 64; ++d) acc += At[d * 64 + e] * Wt[d * 128 + cl];
            WeffT[((long)b * 512 + cc + cl) * 512 + h * 64 + e] = f2bf(acc);
        }
    }
}

// ---------- depthwise 3x3 conv, x-chunked for occupancy ----------
__global__ __launch_bounds__(256)
void k_conv1_gelu(const unsigned short* __restrict__ V,
                  const float* __restrict__ w, unsigned short* __restrict__ g) {
    const int x0 = blockIdx.x * 16;
    const int y  = blockIdx.y;
    const int b  = blockIdx.z;
    const int c0 = threadIdx.x * 2;
    float wq0[9], wq1[9];
#pragma unroll
    for (int i = 0; i < 9; ++i) { wq0[i] = w[c0 * 9 + i]; wq1[i] = w[(c0 + 1) * 9 + i]; }
    const long pixbase = (long)b * 16384;

    auto ld = [&](int yy, int xx) -> float2 {
        if (yy < 0 || yy > 127 || xx < 0 || xx > 127) return make_float2(0.f, 0.f);
        return bfpair(*(const unsigned*)(V + (pixbase + (long)yy * 128 + xx) * 1536 + c0));
    };

    float2 win[3][3];
#pragma unroll
    for (int ky = 0; ky < 3; ++ky) {
        win[ky][0] = ld(y + ky - 1, x0 - 1);
        win[ky][1] = ld(y + ky - 1, x0);
    }
    for (int xi = 0; xi < 16; ++xi) {
        const int x = x0 + xi;
#pragma unroll
        for (int ky = 0; ky < 3; ++ky) win[ky][2] = ld(y + ky - 1, x + 1);
        float a0 = 0.f, a1 = 0.f;
#pragma unroll
        for (int ky = 0; ky < 3; ++ky)
#pragma unroll
            for (int kx = 0; kx < 3; ++kx) {
                a0 += win[ky][kx].x * wq0[ky * 3 + kx];
                a1 += win[ky][kx].y * wq1[ky * 3 + kx];
            }
        a0 = 0.5f * a0 * (1.f + erff(a0 * 0.70710678118654752f));
        a1 = 0.5f * a1 * (1.f + erff(a1 * 0.70710678118654752f));
        const unsigned up = (unsigned)f2bf(a0) | ((unsigned)f2bf(a1) << 16);
        *(unsigned*)(g + (pixbase + (long)y * 128 + x) * 512 + c0) = up;
#pragma unroll
        for (int ky = 0; ky < 3; ++ky) {
            win[ky][0] = win[ky][1];
            win[ky][1] = win[ky][2];
        }
    }
}

__global__ __launch_bounds__(256)
void k_conv2_add(const unsigned short* __restrict__ gin,
                 const float* __restrict__ w, float* __restrict__ out) {
    const int x0 = blockIdx.x * 16;
    const int y  = blockIdx.y;
    const int b  = blockIdx.z;
    const int c0 = threadIdx.x * 2;
    float wq0[9], wq1[9];
#pragma unroll
    for (int i = 0; i < 9; ++i) { wq0[i] = w[c0 * 9 + i]; wq1[i] = w[(c0 + 1) * 9 + i]; }
    const long pixbase = (long)b * 16384;

    auto ld = [&](int yy, int xx) -> float2 {
        if (yy < 0 || yy > 127 || xx < 0 || xx > 127) return make_float2(0.f, 0.f);
        return bfpair(*(const unsigned*)(gin + (pixbase + (long)yy * 128 + xx) * 512 + c0));
    };

    float2 win[3][3];
#pragma unroll
    for (int ky = 0; ky < 3; ++ky) {
        win[ky][0] = ld(y + ky - 1, x0 - 1);
        win[ky][1] = ld(y + ky - 1, x0);
    }
    for (int xi = 0; xi < 16; ++xi) {
        const int x = x0 + xi;
#pragma unroll
        for (int ky = 0; ky < 3; ++ky) win[ky][2] = ld(y + ky - 1, x + 1);
        float a0 = 0.f, a1 = 0.f;
#pragma unroll
        for (int ky = 0; ky < 3; ++ky)
#pragma unroll
            for (int kx = 0; kx < 3; ++kx) {
                a0 += win[ky][kx].x * wq0[ky * 3 + kx];
                a1 += win[ky][kx].y * wq1[ky * 3 + kx];
            }
        float2* o = (float2*)(out + (pixbase + (long)y * 128 + x) * 512 + c0);
        float2 p = *o;
        p.x += a0; p.y += a1;
        *o = p;
#pragma unroll
        for (int ky = 0; ky < 3; ++ky) {
            win[ky][0] = win[ky][1];
            win[ky][1] = win[ky][2];
        }
    }
}

// ---------- launch ----------
extern "C" void kernel_launch(void* const* d_in, const int* in_sizes, int n_in,
                              void* d_out, int out_size, void* d_ws, size_t ws_size,
                              hipStream_t stream) {
    const float* x_in    = (const float*)d_in[0];
    const float* Wq      = (const float*)d_in[1];
    const float* Wk      = (const float*)d_in[2];
    const float* Wv      = (const float*)d_in[3];
    const float* rescale = (const float*)d_in[4];
    const float* Wp      = (const float*)d_in[5];
    const float* bp      = (const float*)d_in[6];
    const float* c1w     = (const float*)d_in[7];
    const float* c2w     = (const float*)d_in[8];
    float* out = (float*)d_out;

    char* ws = (char*)d_ws;
    unsigned short* QKV = (unsigned short*)(ws);                  // [65536][1536] bf16
    unsigned short* XBF = (unsigned short*)(ws + 201326592LL);    // x bf16, reused as gelu buf
    unsigned short* WCT = (unsigned short*)(ws + 268435456LL);    // WcatT [1536][512] bf16
    float*          SSQ = (float*)(ws + 270008320LL);             // [4][1024]
    float*          ATT = (float*)(ws + 270024704LL);             // [4][8][64][64]
    unsigned short* WEF = (unsigned short*)(ws + 270548992LL);    // WeffT [4][512][512] bf16

    (void)hipMemsetAsync(SSQ, 0, 16384 + 524288, stream);

    k_f32_to_bf16<<<dim3(16384), dim3(256), 0, stream>>>(x_in, XBF);
    k_build_wcat<<<dim3(16, 48), dim3(256), 0, stream>>>(Wq, Wk, Wv, WCT);

    // QKV = x @ [Wq|Wk|Wv]  (M=65536, N=1536, K=512) -> bf16, fused Q/K col-sumsq
    gemm_mfma<1, 0, 1><<<dim3(12, 512, 1), dim3(256), 0, stream>>>(
        XBF, WCT, (void*)QKV, nullptr, SSQ, 512, 512, 1536, 512, 0L, 0L, 0L);

    k_attn_partial<<<dim3(64, 8, 4), dim3(256), 0, stream>>>(QKV, ATT);
    k_softmax<<<dim3(32), dim3(64), 0, stream>>>(ATT, SSQ, rescale);
    k_weff<<<dim3(8, 4), dim3(256), 0, stream>>>(ATT, Wp, WEF);

    // out_c = V @ Weff^T + bp  (batched: M=16384, N=512, K=512)
    gemm_mfma<0, 1, 0><<<dim3(4, 128, 4), dim3(256), 0, stream>>>(
        QKV + 1024, WEF, (void*)out, bp, nullptr, 1536, 512, 512, 512,
        (long)16384 * 1536, (long)512 * 512, (long)16384 * 512);

    // positional branch: dwconv3x3 -> gelu -> dwconv3x3, += into out
    k_conv1_gelu<<<dim3(8, 128, 4), dim3(256), 0, stream>>>(QKV + 1024, c1w, XBF);
    k_conv2_add<<<dim3(8, 128, 4), dim3(256), 0, stream>>>(XBF, c2w, out);
}

// Round 6
// 516.924 us; speedup vs baseline: 1.1819x; 1.1819x over previous
//
#include <hip/hip_runtime.h>
#include <hip/hip_bf16.h>

// ---------- types & helpers ----------
typedef __attribute__((ext_vector_type(4))) float f32x4;
typedef __attribute__((ext_vector_type(8))) short s16x8;

__device__ __forceinline__ unsigned short f2bf(float f) {
    __hip_bfloat16 h = __float2bfloat16(f);
    return __builtin_bit_cast(unsigned short, h);
}
__device__ __forceinline__ float bf2f(unsigned short u) {
    return __builtin_bit_cast(float, ((unsigned)u) << 16);
}
__device__ __forceinline__ float2 bfpair(unsigned u) {
    float2 r;
    r.x = __builtin_bit_cast(float, u << 16);
    r.y = __builtin_bit_cast(float, u & 0xffff0000u);
    return r;
}
__device__ __forceinline__ void gload_lds16(const void* g, void* l) {
    __builtin_amdgcn_global_load_lds(
        (const __attribute__((address_space(1))) void*)g,
        (__attribute__((address_space(3))) void*)l, 16, 0, 0);
}

// ---------- convert x (fp32 -> bf16), 8 elems/thread, exact grid ----------
__global__ void k_f32_to_bf16(const float* __restrict__ in, unsigned short* __restrict__ out) {
    const long i = (long)blockIdx.x * 256 + threadIdx.x;   // 4,194,304 threads
    const float4 a = ((const float4*)in)[i * 2];
    const float4 b = ((const float4*)in)[i * 2 + 1];
    union { unsigned short h[8]; uint4 u; } r;
    r.h[0] = f2bf(a.x); r.h[1] = f2bf(a.y); r.h[2] = f2bf(a.z); r.h[3] = f2bf(a.w);
    r.h[4] = f2bf(b.x); r.h[5] = f2bf(b.y); r.h[6] = f2bf(b.z); r.h[7] = f2bf(b.w);
    ((uint4*)out)[i] = r.u;
}

// ---------- build W_cat^T [1536][512] bf16, coalesced via LDS 32x32 transpose ----------
__global__ __launch_bounds__(256)
void k_build_wcat(const float* __restrict__ Wq, const float* __restrict__ Wk,
                  const float* __restrict__ Wv, unsigned short* __restrict__ WcatT) {
    __shared__ float t[32][33];
    const int k0 = blockIdx.x * 32;          // 16 tiles over k
    const int j0 = blockIdx.y * 32;          // 48 tiles over j
    const float* src = (j0 < 512) ? Wq : (j0 < 1024 ? Wk : Wv);
    const int jc0 = j0 & 511;
    const int r = threadIdx.x >> 5, c = threadIdx.x & 31;
#pragma unroll
    for (int rr = 0; rr < 4; ++rr) {
        const int k = k0 + r + rr * 8;
        t[c][r + rr * 8] = src[(long)k * 512 + jc0 + c];   // coalesced read (j contiguous)
    }
    __syncthreads();
#pragma unroll
    for (int rr = 0; rr < 4; ++rr) {
        const int j = j0 + r + rr * 8;
        WcatT[(long)j * 512 + k0 + c] = f2bf(t[r + rr * 8][c]);  // coalesced write (k contiguous)
    }
}

// ---------- MFMA bf16 GEMM 128x128 (m97-style, proven 123us @ QKV shape) ----------
// Optional fused column sum-of-squares for cols < 1024 (Q,K norms), batch = row>>14.
#define BM 128
#define BN 128
#define BK 64

template<int OUT_BF16, int BIAS, int SSQF>
__global__ __launch_bounds__(256, 2)
void gemm_mfma(const unsigned short* __restrict__ A, const unsigned short* __restrict__ B,
               void* __restrict__ C_, const float* __restrict__ bias, float* __restrict__ ssq,
               int lda, int ldb, int ldc, int K, long sA, long sB, long sC) {
    __shared__ __align__(16) unsigned short As[BM * BK];
    __shared__ __align__(16) unsigned short Bs[BN * BK];
    __shared__ float ssq_lds[128];
    const int tid  = threadIdx.x;
    const int wave = tid >> 6;
    const int lane = tid & 63;
    const int wm = wave >> 1, wn = wave & 1;
    const int bm0 = blockIdx.y * BM;
    const int bn0 = blockIdx.x * BN;
    const long bz = blockIdx.z;
    A += bz * sA;
    B += bz * sB;

    const int l15 = lane & 15;
    const int l4  = lane >> 4;

    if (SSQF && tid < 128) ssq_lds[tid] = 0.f;

    f32x4 acc[4][4];
#pragma unroll
    for (int i = 0; i < 4; ++i)
#pragma unroll
        for (int j = 0; j < 4; ++j) acc[i][j] = (f32x4){0.f, 0.f, 0.f, 0.f};

    const int srow    = wave * 8 + (lane >> 3);
    const int schunk0 = lane & 7;
    const int arow_b  = wm * 64 + l15;
    const int brow_b  = wn * 64 + l15;

    const int nk = K / BK;
    for (int kt = 0; kt < nk; ++kt) {
        const int k0 = kt * BK;
#pragma unroll
        for (int i = 0; i < 4; ++i) {
            const int r  = i * 32 + srow;
            const int gc = schunk0 ^ (r & 7);
            gload_lds16(A + (long)(bm0 + r) * lda + (k0 + gc * 8), &As[(i * 32 + wave * 8) * BK]);
            gload_lds16(B + (long)(bn0 + r) * ldb + (k0 + gc * 8), &Bs[(i * 32 + wave * 8) * BK]);
        }
        __syncthreads();
        s16x8 af[4][2], bfr[4][2];
#pragma unroll
        for (int mi = 0; mi < 4; ++mi) {
            const int row = arow_b + mi * 16;
#pragma unroll
            for (int ki = 0; ki < 2; ++ki) {
                const int ch = (ki * 4 + l4) ^ (row & 7);
                af[mi][ki] = *(const s16x8*)&As[row * BK + ch * 8];
            }
        }
#pragma unroll
        for (int ni = 0; ni < 4; ++ni) {
            const int row = brow_b + ni * 16;
#pragma unroll
            for (int ki = 0; ki < 2; ++ki) {
                const int ch = (ki * 4 + l4) ^ (row & 7);
                bfr[ni][ki] = *(const s16x8*)&Bs[row * BK + ch * 8];
            }
        }
#pragma unroll
        for (int ki = 0; ki < 2; ++ki)
#pragma unroll
            for (int mi = 0; mi < 4; ++mi)
#pragma unroll
                for (int ni = 0; ni < 4; ++ni)
                    acc[mi][ni] = __builtin_amdgcn_mfma_f32_16x16x32_bf16(
                        af[mi][ki], bfr[ni][ki], acc[mi][ni], 0, 0, 0);
        __syncthreads();
    }

    // epilogue: C/D map col=lane&15, row=(lane>>4)*4+reg  [m89-verified]
#pragma unroll
    for (int mi = 0; mi < 4; ++mi) {
        const int row0 = bm0 + wm * 64 + mi * 16 + l4 * 4;
#pragma unroll
        for (int ni = 0; ni < 4; ++ni) {
            const int col = bn0 + wn * 64 + ni * 16 + l15;
            if (OUT_BF16) {
                unsigned short* C = (unsigned short*)C_ + bz * sC;
#pragma unroll
                for (int j = 0; j < 4; ++j)
                    C[(long)(row0 + j) * ldc + col] = f2bf(acc[mi][ni][j]);
            } else {
                float* C = (float*)C_ + bz * sC;
                const float bv = BIAS ? bias[col] : 0.f;
#pragma unroll
                for (int j = 0; j < 4; ++j)
                    C[(long)(row0 + j) * ldc + col] = acc[mi][ni][j] + bv;
            }
        }
    }
    // fused Q/K column sum-of-squares
    if (SSQF && bn0 < 1024) {
        const int b = bm0 >> 14;   // 16384 rows per batch
#pragma unroll
        for (int ni = 0; ni < 4; ++ni) {
            float s = 0.f;
#pragma unroll
            for (int mi = 0; mi < 4; ++mi)
#pragma unroll
                for (int j = 0; j < 4; ++j) s += acc[mi][ni][j] * acc[mi][ni][j];
            s += __shfl_xor(s, 16);
            s += __shfl_xor(s, 32);
            if (l4 == 0) atomicAdd(&ssq_lds[wn * 64 + ni * 16 + l15], s);
        }
        __syncthreads();
        if (tid < 128) atomicAdd(&ssq[b * 1024 + bn0 + tid], ssq_lds[tid]);
    }
}

// ---------- MFMA attn logits: attn[b,h,d,e] += sum_n K[n,d]*Q[n,e] over this chunk ----------
// Q,K tiles staged TRANSPOSED in LDS ([chan][token], XOR-swizzled); wave w owns d-frag w.
__global__ __launch_bounds__(256)
void k_attn_mfma(const unsigned short* __restrict__ QKV, float* __restrict__ attn) {
    __shared__ __align__(16) unsigned short KT[64 * 64];  // [d][n] swizzled
    __shared__ __align__(16) unsigned short QT[64 * 64];  // [e][n] swizzled
    const int t = threadIdx.x, wave = t >> 6, lane = t & 63;
    const int chunk = blockIdx.x, h = blockIdx.y, b = blockIdx.z;
    const int l15 = lane & 15, l4 = lane >> 4;

    f32x4 acc[4];
#pragma unroll
    for (int i = 0; i < 4; ++i) acc[i] = (f32x4){0.f, 0.f, 0.f, 0.f};

    const long base = ((long)b * 16384 + chunk * 1024) * 1536 + h * 64;
    const int e0 = (t & 31) * 2;          // column pair this thread stages
    const int r0 = t >> 5;                // row offset (8 rows/pass)
    const int swz = ((e0 >> 1) & 7) * 8;  // same for e0 and e0+1

    const int arow = wave * 16 + l15;     // A-frag row (d), fixed per lane
    const int aswz = (arow >> 1) & 7;

    for (int tile = 0; tile < 16; ++tile) {
        __syncthreads();
        // stage 64 tokens x 64 chans of Q and K, transposed + swizzled
#pragma unroll
        for (int i = 0; i < 8; ++i) {
            const int r = r0 + i * 8;     // local token
            const long g = base + (long)(tile * 64 + r) * 1536 + e0;
            const unsigned uq = *(const unsigned*)(QKV + g);
            const unsigned uk = *(const unsigned*)(QKV + g + 512);
            const int xr = r ^ swz;
            QT[e0 * 64 + xr]       = (unsigned short)(uq & 0xffff);
            QT[(e0 + 1) * 64 + xr] = (unsigned short)(uq >> 16);
            KT[e0 * 64 + xr]       = (unsigned short)(uk & 0xffff);
            KT[(e0 + 1) * 64 + xr] = (unsigned short)(uk >> 16);
        }
        __syncthreads();
        // compute: wave owns d rows [wave*16, wave*16+16)
        s16x8 af[2], bfr[4][2];
#pragma unroll
        for (int ks = 0; ks < 2; ++ks)
            af[ks] = *(const s16x8*)&KT[arow * 64 + ((ks * 4 + l4) ^ aswz) * 8];
#pragma unroll
        for (int ni = 0; ni < 4; ++ni) {
            const int brow = ni * 16 + l15;
            const int bswz = (brow >> 1) & 7;
#pragma unroll
            for (int ks = 0; ks < 2; ++ks)
                bfr[ni][ks] = *(const s16x8*)&QT[brow * 64 + ((ks * 4 + l4) ^ bswz) * 8];
        }
#pragma unroll
        for (int ks = 0; ks < 2; ++ks)
#pragma unroll
            for (int ni = 0; ni < 4; ++ni)
                acc[ni] = __builtin_amdgcn_mfma_f32_16x16x32_bf16(
                    af[ks], bfr[ni][ks], acc[ni], 0, 0, 0);
    }

    float* arow_out = attn + ((long)(b * 8 + h)) * 4096;
#pragma unroll
    for (int ni = 0; ni < 4; ++ni) {
        const int e = ni * 16 + l15;
#pragma unroll
        for (int j = 0; j < 4; ++j) {
            const int d = wave * 16 + l4 * 4 + j;
            atomicAdd(&arow_out[d * 64 + e], acc[ni][j]);
        }
    }
}

// ---------- normalize + softmax over e ----------
__global__ void k_softmax(float* __restrict__ attn, const float* __restrict__ sumsq,
                          const float* __restrict__ rescale) {
    const int bh = blockIdx.x;
    const int b = bh >> 3, h = bh & 7;
    const int d = threadIdx.x; // 64
    const float rs   = rescale[h];
    const float invk = rsqrtf(sumsq[b * 1024 + 512 + h * 64 + d]);
    __shared__ float invq[64];
    invq[d] = rsqrtf(sumsq[b * 1024 + h * 64 + d]);
    __syncthreads();
    float* row = attn + ((long)bh * 64 + d) * 64;
    float mx = -1e30f;
#pragma unroll
    for (int e = 0; e < 64; ++e) mx = fmaxf(mx, row[e] * invk * invq[e] * rs);
    float s = 0.f;
#pragma unroll
    for (int e = 0; e < 64; ++e) {
        const float l = expf(row[e] * invk * invq[e] * rs - mx);
        row[e] = l;
        s += l;
    }
    const float inv = 1.f / s;
#pragma unroll
    for (int e = 0; e < 64; ++e) row[e] *= inv;
}

// ---------- Weff^T[b][cout][h*64+e] = sum_d attn[b,h,d,e] * Wp[h*64+d][cout] ----------
__global__ __launch_bounds__(256)
void k_weff(const float* __restrict__ attn, const float* __restrict__ Wp,
            unsigned short* __restrict__ WeffT) {
    const int h = blockIdx.x, b = blockIdx.y;
    __shared__ float At[64 * 64];   // [d][e]
    __shared__ float Wt[64 * 128];  // [d][c]
    const int t = threadIdx.x;
    const float* arow = attn + ((long)(b * 8 + h)) * 4096;
    for (int i = 0; i < 16; ++i) At[i * 256 + t] = arow[i * 256 + t];
    const int e = t & 63, cs = t >> 6;
    for (int cc = 0; cc < 512; cc += 128) {
        __syncthreads();
        for (int i = 0; i < 32; ++i) {
            const int idx = i * 256 + t;
            const int d = idx >> 7, c = idx & 127;
            Wt[idx] = Wp[(long)(h * 64 + d) * 512 + cc + c];
        }
        __syncthreads();
        for (int i = 0; i < 32; ++i) {
            const int cl = cs * 32 + i;
            float acc = 0.f;
#pragma unroll
            for (int d = 0; d < 64; ++d) acc += At[d * 64 + e] * Wt[d * 128 + cl];
            WeffT[((long)b * 512 + cc + cl) * 512 + h * 64 + e] = f2bf(acc);
        }
    }
}

// ---------- depthwise 3x3 conv, x-chunked for occupancy ----------
__global__ __launch_bounds__(256)
void k_conv1_gelu(const unsigned short* __restrict__ V,
                  const float* __restrict__ w, unsigned short* __restrict__ g) {
    const int x0 = blockIdx.x * 16;
    const int y  = blockIdx.y;
    const int b  = blockIdx.z;
    const int c0 = threadIdx.x * 2;
    float wq0[9], wq1[9];
#pragma unroll
    for (int i = 0; i < 9; ++i) { wq0[i] = w[c0 * 9 + i]; wq1[i] = w[(c0 + 1) * 9 + i]; }
    const long pixbase = (long)b * 16384;

    auto ld = [&](int yy, int xx) -> float2 {
        if (yy < 0 || yy > 127 || xx < 0 || xx > 127) return make_float2(0.f, 0.f);
        return bfpair(*(const unsigned*)(V + (pixbase + (long)yy * 128 + xx) * 1536 + c0));
    };

    float2 win[3][3];
#pragma unroll
    for (int ky = 0; ky < 3; ++ky) {
        win[ky][0] = ld(y + ky - 1, x0 - 1);
        win[ky][1] = ld(y + ky - 1, x0);
    }
    for (int xi = 0; xi < 16; ++xi) {
        const int x = x0 + xi;
#pragma unroll
        for (int ky = 0; ky < 3; ++ky) win[ky][2] = ld(y + ky - 1, x + 1);
        float a0 = 0.f, a1 = 0.f;
#pragma unroll
        for (int ky = 0; ky < 3; ++ky)
#pragma unroll
            for (int kx = 0; kx < 3; ++kx) {
                a0 += win[ky][kx].x * wq0[ky * 3 + kx];
                a1 += win[ky][kx].y * wq1[ky * 3 + kx];
            }
        a0 = 0.5f * a0 * (1.f + erff(a0 * 0.70710678118654752f));
        a1 = 0.5f * a1 * (1.f + erff(a1 * 0.70710678118654752f));
        const unsigned up = (unsigned)f2bf(a0) | ((unsigned)f2bf(a1) << 16);
        *(unsigned*)(g + (pixbase + (long)y * 128 + x) * 512 + c0) = up;
#pragma unroll
        for (int ky = 0; ky < 3; ++ky) {
            win[ky][0] = win[ky][1];
            win[ky][1] = win[ky][2];
        }
    }
}

__global__ __launch_bounds__(256)
void k_conv2_add(const unsigned short* __restrict__ gin,
                 const float* __restrict__ w, float* __restrict__ out) {
    const int x0 = blockIdx.x * 16;
    const int y  = blockIdx.y;
    const int b  = blockIdx.z;
    const int c0 = threadIdx.x * 2;
    float wq0[9], wq1[9];
#pragma unroll
    for (int i = 0; i < 9; ++i) { wq0[i] = w[c0 * 9 + i]; wq1[i] = w[(c0 + 1) * 9 + i]; }
    const long pixbase = (long)b * 16384;

    auto ld = [&](int yy, int xx) -> float2 {
        if (yy < 0 || yy > 127 || xx < 0 || xx > 127) return make_float2(0.f, 0.f);
        return bfpair(*(const unsigned*)(gin + (pixbase + (long)yy * 128 + xx) * 512 + c0));
    };

    float2 win[3][3];
#pragma unroll
    for (int ky = 0; ky < 3; ++ky) {
        win[ky][0] = ld(y + ky - 1, x0 - 1);
        win[ky][1] = ld(y + ky - 1, x0);
    }
    for (int xi = 0; xi < 16; ++xi) {
        const int x = x0 + xi;
#pragma unroll
        for (int ky = 0; ky < 3; ++ky) win[ky][2] = ld(y + ky - 1, x + 1);
        float a0 = 0.f, a1 = 0.f;
#pragma unroll
        for (int ky = 0; ky < 3; ++ky)
#pragma unroll
            for (int kx = 0; kx < 3; ++kx) {
                a0 += win[ky][kx].x * wq0[ky * 3 + kx];
                a1 += win[ky][kx].y * wq1[ky * 3 + kx];
            }
        float2* o = (float2*)(out + (pixbase + (long)y * 128 + x) * 512 + c0);
        float2 p = *o;
        p.x += a0; p.y += a1;
        *o = p;
#pragma unroll
        for (int ky = 0; ky < 3; ++ky) {
            win[ky][0] = win[ky][1];
            win[ky][1] = win[ky][2];
        }
    }
}

// ---------- launch ----------
extern "C" void kernel_launch(void* const* d_in, const int* in_sizes, int n_in,
                              void* d_out, int out_size, void* d_ws, size_t ws_size,
                              hipStream_t stream) {
    const float* x_in    = (const float*)d_in[0];
    const float* Wq      = (const float*)d_in[1];
    const float* Wk      = (const float*)d_in[2];
    const float* Wv      = (const float*)d_in[3];
    const float* rescale = (const float*)d_in[4];
    const float* Wp      = (const float*)d_in[5];
    const float* bp      = (const float*)d_in[6];
    const float* c1w     = (const float*)d_in[7];
    const float* c2w     = (const float*)d_in[8];
    float* out = (float*)d_out;

    char* ws = (char*)d_ws;
    unsigned short* QKV = (unsigned short*)(ws);                  // [65536][1536] bf16
    unsigned short* XBF = (unsigned short*)(ws + 201326592LL);    // x bf16, reused as gelu buf
    unsigned short* WCT = (unsigned short*)(ws + 268435456LL);    // WcatT [1536][512] bf16
    float*          SSQ = (float*)(ws + 270008320LL);             // [4][1024]
    float*          ATT = (float*)(ws + 270024704LL);             // [4][8][64][64]
    unsigned short* WEF = (unsigned short*)(ws + 270548992LL);    // WeffT [4][512][512] bf16

    (void)hipMemsetAsync(SSQ, 0, 16384 + 524288, stream);

    k_f32_to_bf16<<<dim3(16384), dim3(256), 0, stream>>>(x_in, XBF);
    k_build_wcat<<<dim3(16, 48), dim3(256), 0, stream>>>(Wq, Wk, Wv, WCT);

    // QKV = x @ [Wq|Wk|Wv]  (M=65536, N=1536, K=512) -> bf16, fused Q/K col-sumsq
    gemm_mfma<1, 0, 1><<<dim3(12, 512, 1), dim3(256), 0, stream>>>(
        XBF, WCT, (void*)QKV, nullptr, SSQ, 512, 512, 1536, 512, 0L, 0L, 0L);

    // attn logits via MFMA (16 chunks of 1024 tokens, atomic partial sums)
    k_attn_mfma<<<dim3(16, 8, 4), dim3(256), 0, stream>>>(QKV, ATT);
    k_softmax<<<dim3(32), dim3(64), 0, stream>>>(ATT, SSQ, rescale);
    k_weff<<<dim3(8, 4), dim3(256), 0, stream>>>(ATT, Wp, WEF);

    // out_c = V @ Weff^T + bp  (batched: M=16384, N=512, K=512)
    gemm_mfma<0, 1, 0><<<dim3(4, 128, 4), dim3(256), 0, stream>>>(
        QKV + 1024, WEF, (void*)out, bp, nullptr, 1536, 512, 512, 512,
        (long)16384 * 1536, (long)512 * 512, (long)16384 * 512);

    // positional branch: dwconv3x3 -> gelu -> dwconv3x3, += into out
    k_conv1_gelu<<<dim3(8, 128, 4), dim3(256), 0, stream>>>(QKV + 1024, c1w, XBF);
    k_conv2_add<<<dim3(8, 128, 4), dim3(256), 0, stream>>>(XBF, c2w, out);
}